// Round 1
// baseline (4456.685 us; speedup 1.0000x reference)
//
#include <hip/hip_runtime.h>
#include <hip/hip_bf16.h>

// Problem constants (fixed in the reference module)
#define N1C  100000
#define N2C  20000
#define DIN_ 128
#define DH_  256
#define DOUT_ 128

// ---------------------------------------------------------------------------
// Scatter-add: for each edge e, agg[dst[e], :] += X[src[e], :]; cnt[dst[e]] += 1
// One (edge, float4-chunk) per thread. D must be a multiple of 4.
// ---------------------------------------------------------------------------
__global__ __launch_bounds__(256) void scatter_add_kernel(
    const float* __restrict__ X, const int* __restrict__ src,
    const int* __restrict__ dst, float* __restrict__ agg,
    float* __restrict__ cnt, int E, int D)
{
    const int t = blockIdx.x * 256 + threadIdx.x;
    const int lanes = D >> 2;              // float4 chunks per row
    const int e = t / lanes;               // lanes is a power of two -> shift
    if (e >= E) return;
    const int l = t - e * lanes;
    const int s = src[e];
    const int d = dst[e];
    const float4 v = *(const float4*)(X + (size_t)s * D + (l << 2));
    float* p = agg + (size_t)d * D + (l << 2);
    atomicAdd(p + 0, v.x);
    atomicAdd(p + 1, v.y);
    atomicAdd(p + 2, v.z);
    atomicAdd(p + 3, v.w);
    if (l == 0) atomicAdd(cnt + d, 1.0f);
}

// ---------------------------------------------------------------------------
// Scale rows: agg[i,:] *= 1 / max(cnt[i], 1)   (turn sum into mean)
// ---------------------------------------------------------------------------
__global__ __launch_bounds__(256) void scale_rows_kernel(
    float* __restrict__ agg, const float* __restrict__ cnt, int n, int D)
{
    const int t = blockIdx.x * 256 + threadIdx.x;
    const int lanes = D >> 2;
    const int i = t / lanes;
    if (i >= n) return;
    const int l = t - i * lanes;
    const float r = 1.0f / fmaxf(cnt[i], 1.0f);
    float4* p = (float4*)(agg + (size_t)i * D + (l << 2));
    float4 v = *p;
    v.x *= r; v.y *= r; v.z *= r; v.w *= r;
    *p = v;
}

// ---------------------------------------------------------------------------
// Dual-A GEMM: C[M,N] = A1 @ B1^T + A2 @ B2^T
//   A1,A2: [M,K] row-major (stride K); B1,B2: [N,K] row-major (stride K)
// Block: 256 threads, 64x64 tile, 4x4 outputs/thread, BK=16.
// ---------------------------------------------------------------------------
#define BM 64
#define BN 64
#define BK 16

__global__ __launch_bounds__(256) void gemm_dual_kernel(
    const float* __restrict__ A1, const float* __restrict__ B1,
    const float* __restrict__ A2, const float* __restrict__ B2,
    float* __restrict__ C, int M, int N, int K)
{
    __shared__ float As[BK][BM + 4];   // +4 keeps float4 rows 16B-aligned
    __shared__ float Bs[BK][BN + 4];

    const int tid = threadIdx.x;
    const int m0 = blockIdx.x * BM;
    const int n0 = blockIdx.y * BN;
    const int tm = (tid >> 4) << 2;    // 0..60
    const int tn = (tid & 15) << 2;    // 0..60
    const int lr = tid >> 2;           // 0..63: row within tile for loading
    const int lk = (tid & 3) << 2;     // 0,4,8,12: k offset for float4 load

    float acc[4][4] = {{0.f, 0.f, 0.f, 0.f}, {0.f, 0.f, 0.f, 0.f},
                       {0.f, 0.f, 0.f, 0.f}, {0.f, 0.f, 0.f, 0.f}};

    for (int phase = 0; phase < 2; ++phase) {
        const float* __restrict__ A = phase ? A2 : A1;
        const float* __restrict__ B = phase ? B2 : B1;
        for (int k0 = 0; k0 < K; k0 += BK) {
            float4 av = make_float4(0.f, 0.f, 0.f, 0.f);
            const int ga = m0 + lr;
            if (ga < M) av = *(const float4*)(A + (size_t)ga * K + k0 + lk);
            const int gb = n0 + lr;  // N always a multiple of BN here
            const float4 bv = *(const float4*)(B + (size_t)gb * K + k0 + lk);

            __syncthreads();  // protect previous iteration's reads
            As[lk + 0][lr] = av.x; As[lk + 1][lr] = av.y;
            As[lk + 2][lr] = av.z; As[lk + 3][lr] = av.w;
            Bs[lk + 0][lr] = bv.x; Bs[lk + 1][lr] = bv.y;
            Bs[lk + 2][lr] = bv.z; Bs[lk + 3][lr] = bv.w;
            __syncthreads();

            #pragma unroll
            for (int k = 0; k < BK; ++k) {
                const float4 a = *(const float4*)&As[k][tm];
                const float4 b = *(const float4*)&Bs[k][tn];
                acc[0][0] += a.x * b.x; acc[0][1] += a.x * b.y;
                acc[0][2] += a.x * b.z; acc[0][3] += a.x * b.w;
                acc[1][0] += a.y * b.x; acc[1][1] += a.y * b.y;
                acc[1][2] += a.y * b.z; acc[1][3] += a.y * b.w;
                acc[2][0] += a.z * b.x; acc[2][1] += a.z * b.y;
                acc[2][2] += a.z * b.z; acc[2][3] += a.z * b.w;
                acc[3][0] += a.w * b.x; acc[3][1] += a.w * b.y;
                acc[3][2] += a.w * b.z; acc[3][3] += a.w * b.w;
            }
        }
    }

    #pragma unroll
    for (int i = 0; i < 4; ++i) {
        const int row = m0 + tm + i;
        if (row < M) {
            float4 o = make_float4(acc[i][0], acc[i][1], acc[i][2], acc[i][3]);
            *(float4*)(C + (size_t)row * N + n0 + tn) = o;
        }
    }
}

// ---------------------------------------------------------------------------
// Epilogue 1: h[i,:] = relu(BN(l2norm(h[i,:] + b2_1)))  over DH=256 columns.
// One wave (64 lanes) per row, 4 floats per lane.
// ---------------------------------------------------------------------------
__global__ __launch_bounds__(256) void epilogue1_kernel(
    float* __restrict__ h, const float* __restrict__ bias,
    const float* __restrict__ gamma, const float* __restrict__ beta,
    const float* __restrict__ mean, const float* __restrict__ var, int n)
{
    const int w = (blockIdx.x * 256 + threadIdx.x) >> 6;
    const int lane = threadIdx.x & 63;
    if (w >= n) return;
    float* row = h + (size_t)w * DH_;
    const int c = lane << 2;

    float4 v = *(float4*)(row + c);
    const float4 bb = *(const float4*)(bias + c);
    v.x += bb.x; v.y += bb.y; v.z += bb.z; v.w += bb.w;

    float ss = v.x * v.x + v.y * v.y + v.z * v.z + v.w * v.w;
    #pragma unroll
    for (int o = 32; o > 0; o >>= 1) ss += __shfl_xor(ss, o);
    const float inv = 1.0f / fmaxf(sqrtf(ss), 1e-12f);

    const float4 g  = *(const float4*)(gamma + c);
    const float4 be = *(const float4*)(beta + c);
    const float4 mn = *(const float4*)(mean + c);
    const float4 vr = *(const float4*)(var + c);

    v.x = fmaxf(g.x * (v.x * inv - mn.x) * rsqrtf(vr.x + 1e-5f) + be.x, 0.f);
    v.y = fmaxf(g.y * (v.y * inv - mn.y) * rsqrtf(vr.y + 1e-5f) + be.y, 0.f);
    v.z = fmaxf(g.z * (v.z * inv - mn.z) * rsqrtf(vr.z + 1e-5f) + be.z, 0.f);
    v.w = fmaxf(g.w * (v.w * inv - mn.w) * rsqrtf(vr.w + 1e-5f) + be.w, 0.f);
    *(float4*)(row + c) = v;
}

// ---------------------------------------------------------------------------
// Epilogue 2: out[i,:] = l2norm(out[i,:] + b2_2)  over DOUT=128 columns.
// One wave per row, 2 floats per lane.
// ---------------------------------------------------------------------------
__global__ __launch_bounds__(256) void epilogue2_kernel(
    float* __restrict__ out, const float* __restrict__ bias, int n)
{
    const int w = (blockIdx.x * 256 + threadIdx.x) >> 6;
    const int lane = threadIdx.x & 63;
    if (w >= n) return;
    float* row = out + (size_t)w * DOUT_;
    const int c = lane << 1;

    float2 v = *(float2*)(row + c);
    const float2 bb = *(const float2*)(bias + c);
    v.x += bb.x; v.y += bb.y;

    float ss = v.x * v.x + v.y * v.y;
    #pragma unroll
    for (int o = 32; o > 0; o >>= 1) ss += __shfl_xor(ss, o);
    const float inv = 1.0f / fmaxf(sqrtf(ss), 1e-12f);

    v.x *= inv; v.y *= inv;
    *(float2*)(row + c) = v;
}

// ---------------------------------------------------------------------------
extern "C" void kernel_launch(void* const* d_in, const int* in_sizes, int n_in,
                              void* d_out, int out_size, void* d_ws, size_t ws_size,
                              hipStream_t stream)
{
    const float* x     = (const float*)d_in[0];
    const int*   src1  = (const int*)d_in[1];
    const int*   dst1  = (const int*)d_in[2];
    const int*   src2  = (const int*)d_in[3];
    const int*   dst2  = (const int*)d_in[4];
    // d_in[5], d_in[6]: n1, n2 scalars — fixed constants (100000, 20000)
    const float* W1_1  = (const float*)d_in[7];
    const float* W2_1  = (const float*)d_in[8];
    const float* b2_1  = (const float*)d_in[9];
    const float* gamma1= (const float*)d_in[10];
    const float* beta1 = (const float*)d_in[11];
    const float* mean1 = (const float*)d_in[12];
    const float* var1  = (const float*)d_in[13];
    const float* W1_2  = (const float*)d_in[14];
    const float* W2_2  = (const float*)d_in[15];
    const float* b2_2  = (const float*)d_in[16];
    float* out = (float*)d_out;

    const int E1 = in_sizes[1];
    const int E2 = in_sizes[3];
    const int n1 = N1C;
    const int n2 = N2C;

    // Workspace layout (floats):
    //   agg1 [n1*DIN] | cnt1 [n1] | agg2 [n2*DH] | cnt2 [n2] | h [n1*DH]
    float* ws   = (float*)d_ws;
    float* agg1 = ws;
    float* cnt1 = agg1 + (size_t)n1 * DIN_;
    float* agg2 = cnt1 + n1;
    float* cnt2 = agg2 + (size_t)n2 * DH_;
    float* h    = cnt2 + n2;

    // Zero the accumulators (one contiguous region)
    const size_t zero_bytes = (size_t)((cnt2 + n2) - ws) * sizeof(float);
    hipMemsetAsync(ws, 0, zero_bytes, stream);

    // --- Layer 1 aggregation: agg1 = segment_mean(x[src1] by dst1) ---
    {
        const long long threads = (long long)E1 * (DIN_ / 4);
        const int blocks = (int)((threads + 255) / 256);
        scatter_add_kernel<<<blocks, 256, 0, stream>>>(x, src1, dst1, agg1, cnt1, E1, DIN_);
        const long long sthreads = (long long)n1 * (DIN_ / 4);
        scale_rows_kernel<<<(int)((sthreads + 255) / 256), 256, 0, stream>>>(agg1, cnt1, n1, DIN_);
    }

    // --- Layer 1 GEMM: h = x[:n1] @ W1_1^T + agg1 @ W2_1^T ---
    {
        dim3 grid((n1 + BM - 1) / BM, DH_ / BN);
        gemm_dual_kernel<<<grid, 256, 0, stream>>>(x, W1_1, agg1, W2_1, h, n1, DH_, DIN_);
    }

    // --- Layer 1 epilogue: bias, l2norm, BN(eval), ReLU ---
    epilogue1_kernel<<<(n1 + 3) / 4, 256, 0, stream>>>(h, b2_1, gamma1, beta1, mean1, var1, n1);

    // --- Layer 2 aggregation: agg2 = segment_mean(h[src2] by dst2) ---
    {
        const long long threads = (long long)E2 * (DH_ / 4);
        const int blocks = (int)((threads + 255) / 256);
        scatter_add_kernel<<<blocks, 256, 0, stream>>>(h, src2, dst2, agg2, cnt2, E2, DH_);
        const long long sthreads = (long long)n2 * (DH_ / 4);
        scale_rows_kernel<<<(int)((sthreads + 255) / 256), 256, 0, stream>>>(agg2, cnt2, n2, DH_);
    }

    // --- Layer 2 GEMM: out = h[:n2] @ W1_2^T + agg2 @ W2_2^T ---
    {
        dim3 grid((n2 + BM - 1) / BM, DOUT_ / BN);
        gemm_dual_kernel<<<grid, 256, 0, stream>>>(h, W1_2, agg2, W2_2, out, n2, DOUT_, DH_);
    }

    // --- Layer 2 epilogue: bias, l2norm ---
    epilogue2_kernel<<<(n2 + 3) / 4, 256, 0, stream>>>(out, b2_2, n2);
}

// Round 2
// 1159.310 us; speedup vs baseline: 3.8443x; 3.8443x over previous
//
#include <hip/hip_runtime.h>
#include <hip/hip_bf16.h>

// Problem constants (fixed in the reference module)
#define N1C  100000
#define N2C  20000
#define DIN_ 128
#define DH_  256
#define DOUT_ 128

// ---------------------------------------------------------------------------
// CSR build step 1: histogram of dst
// ---------------------------------------------------------------------------
__global__ __launch_bounds__(256) void hist_kernel(
    const int* __restrict__ dst, int* __restrict__ cnt, int E)
{
    const int e = blockIdx.x * 256 + threadIdx.x;
    if (e < E) atomicAdd(&cnt[dst[e]], 1);
}

// ---------------------------------------------------------------------------
// CSR build step 2: exclusive scan over counts (single block, 1024 threads).
// Reads cnt[i], writes off[i] (exclusive prefix) and cursor[i] (same value;
// cursor may alias cnt — each index is read before it is written).
// Also writes off[n] = total.
// ---------------------------------------------------------------------------
__global__ __launch_bounds__(1024) void exscan_kernel(
    const int* __restrict__ cnt, int* __restrict__ off,
    int* __restrict__ cursor, int n)
{
    __shared__ int wsum[16];
    __shared__ int woff[16];
    __shared__ int s_carry;
    __shared__ int s_total;
    const int lane = threadIdx.x & 63;
    const int wid  = threadIdx.x >> 6;
    if (threadIdx.x == 0) s_carry = 0;
    __syncthreads();
    for (int base = 0; base < n; base += 1024) {
        const int i = base + (int)threadIdx.x;
        const int v = (i < n) ? cnt[i] : 0;
        int s = v;                                // inclusive scan within wave
        #pragma unroll
        for (int o = 1; o < 64; o <<= 1) {
            int t = __shfl_up(s, (unsigned)o);
            if (lane >= o) s += t;
        }
        if (lane == 63) wsum[wid] = s;
        __syncthreads();
        if (wid == 0) {
            int ws = (lane < 16) ? wsum[lane] : 0; // scan the 16 wave sums
            #pragma unroll
            for (int o = 1; o < 16; o <<= 1) {
                int t = __shfl_up(ws, (unsigned)o);
                if (lane >= o) ws += t;
            }
            if (lane < 16) woff[lane] = ws;        // inclusive
            if (lane == 15) s_total = ws;
        }
        __syncthreads();
        const int carry   = s_carry;
        const int woffset = (wid > 0) ? woff[wid - 1] : 0;
        const int exc = carry + woffset + s - v;
        if (i < n) { off[i] = exc; cursor[i] = exc; }
        __syncthreads();
        if (threadIdx.x == 0) s_carry = carry + s_total;
        __syncthreads();
    }
    if (threadIdx.x == 0) off[n] = s_carry;
}

// ---------------------------------------------------------------------------
// CSR build step 3: scatter edge source ids into dst-sorted order
// ---------------------------------------------------------------------------
__global__ __launch_bounds__(256) void scatter_edges_kernel(
    const int* __restrict__ src, const int* __restrict__ dst,
    int* __restrict__ cursor, int* __restrict__ esrc, int E)
{
    const int e = blockIdx.x * 256 + threadIdx.x;
    if (e < E) {
        const int p = atomicAdd(&cursor[dst[e]], 1);
        esrc[p] = src[e];
    }
}

// ---------------------------------------------------------------------------
// Gather segment-mean, D=128: one wave per destination row, float2 per lane.
// agg[w,:] = mean over e in [off[w],off[w+1]) of X[esrc[e],:]
// ---------------------------------------------------------------------------
__global__ __launch_bounds__(256) void gather_mean_128(
    const float* __restrict__ X, const int* __restrict__ off,
    const int* __restrict__ esrc, float* __restrict__ agg, int n)
{
    const int w = (blockIdx.x * 256 + threadIdx.x) >> 6;
    const int lane = threadIdx.x & 63;
    if (w >= n) return;
    const int beg = off[w], end = off[w + 1];
    const int c = lane << 1;
    float ax = 0.f, ay = 0.f;
    int e = beg;
    for (; e + 1 < end; e += 2) {
        const int s0 = esrc[e], s1 = esrc[e + 1];
        const float2 v0 = *(const float2*)(X + (size_t)s0 * DIN_ + c);
        const float2 v1 = *(const float2*)(X + (size_t)s1 * DIN_ + c);
        ax += v0.x + v1.x; ay += v0.y + v1.y;
    }
    if (e < end) {
        const float2 v0 = *(const float2*)(X + (size_t)esrc[e] * DIN_ + c);
        ax += v0.x; ay += v0.y;
    }
    const float r = 1.0f / fmaxf((float)(end - beg), 1.0f);
    float2 o; o.x = ax * r; o.y = ay * r;
    *(float2*)(agg + (size_t)w * DIN_ + c) = o;
}

// ---------------------------------------------------------------------------
// Gather segment-mean, D=256: one wave per destination row, float4 per lane.
// ---------------------------------------------------------------------------
__global__ __launch_bounds__(256) void gather_mean_256(
    const float* __restrict__ X, const int* __restrict__ off,
    const int* __restrict__ esrc, float* __restrict__ agg, int n)
{
    const int w = (blockIdx.x * 256 + threadIdx.x) >> 6;
    const int lane = threadIdx.x & 63;
    if (w >= n) return;
    const int beg = off[w], end = off[w + 1];
    const int c = lane << 2;
    float ax = 0.f, ay = 0.f, az = 0.f, aw = 0.f;
    int e = beg;
    for (; e + 1 < end; e += 2) {
        const int s0 = esrc[e], s1 = esrc[e + 1];
        const float4 v0 = *(const float4*)(X + (size_t)s0 * DH_ + c);
        const float4 v1 = *(const float4*)(X + (size_t)s1 * DH_ + c);
        ax += v0.x + v1.x; ay += v0.y + v1.y;
        az += v0.z + v1.z; aw += v0.w + v1.w;
    }
    if (e < end) {
        const float4 v0 = *(const float4*)(X + (size_t)esrc[e] * DH_ + c);
        ax += v0.x; ay += v0.y; az += v0.z; aw += v0.w;
    }
    const float r = 1.0f / fmaxf((float)(end - beg), 1.0f);
    float4 o; o.x = ax * r; o.y = ay * r; o.z = az * r; o.w = aw * r;
    *(float4*)(agg + (size_t)w * DH_ + c) = o;
}

// ---------------------------------------------------------------------------
// Dual-A GEMM: C[M,N] = A1 @ B1^T + A2 @ B2^T
//   A1,A2: [M,K] row-major (stride K); B1,B2: [N,K] row-major (stride K)
// Block: 256 threads, 64x64 tile, 4x4 outputs/thread, BK=16.
// ---------------------------------------------------------------------------
#define BM 64
#define BN 64
#define BK 16

__global__ __launch_bounds__(256) void gemm_dual_kernel(
    const float* __restrict__ A1, const float* __restrict__ B1,
    const float* __restrict__ A2, const float* __restrict__ B2,
    float* __restrict__ C, int M, int N, int K)
{
    __shared__ float As[BK][BM + 4];
    __shared__ float Bs[BK][BN + 4];

    const int tid = threadIdx.x;
    const int m0 = blockIdx.x * BM;
    const int n0 = blockIdx.y * BN;
    const int tm = (tid >> 4) << 2;
    const int tn = (tid & 15) << 2;
    const int lr = tid >> 2;
    const int lk = (tid & 3) << 2;

    float acc[4][4] = {{0.f, 0.f, 0.f, 0.f}, {0.f, 0.f, 0.f, 0.f},
                       {0.f, 0.f, 0.f, 0.f}, {0.f, 0.f, 0.f, 0.f}};

    for (int phase = 0; phase < 2; ++phase) {
        const float* __restrict__ A = phase ? A2 : A1;
        const float* __restrict__ B = phase ? B2 : B1;
        for (int k0 = 0; k0 < K; k0 += BK) {
            float4 av = make_float4(0.f, 0.f, 0.f, 0.f);
            const int ga = m0 + lr;
            if (ga < M) av = *(const float4*)(A + (size_t)ga * K + k0 + lk);
            const int gb = n0 + lr;
            const float4 bv = *(const float4*)(B + (size_t)gb * K + k0 + lk);

            __syncthreads();
            As[lk + 0][lr] = av.x; As[lk + 1][lr] = av.y;
            As[lk + 2][lr] = av.z; As[lk + 3][lr] = av.w;
            Bs[lk + 0][lr] = bv.x; Bs[lk + 1][lr] = bv.y;
            Bs[lk + 2][lr] = bv.z; Bs[lk + 3][lr] = bv.w;
            __syncthreads();

            #pragma unroll
            for (int k = 0; k < BK; ++k) {
                const float4 a = *(const float4*)&As[k][tm];
                const float4 b = *(const float4*)&Bs[k][tn];
                acc[0][0] += a.x * b.x; acc[0][1] += a.x * b.y;
                acc[0][2] += a.x * b.z; acc[0][3] += a.x * b.w;
                acc[1][0] += a.y * b.x; acc[1][1] += a.y * b.y;
                acc[1][2] += a.y * b.z; acc[1][3] += a.y * b.w;
                acc[2][0] += a.z * b.x; acc[2][1] += a.z * b.y;
                acc[2][2] += a.z * b.z; acc[2][3] += a.z * b.w;
                acc[3][0] += a.w * b.x; acc[3][1] += a.w * b.y;
                acc[3][2] += a.w * b.z; acc[3][3] += a.w * b.w;
            }
        }
    }

    #pragma unroll
    for (int i = 0; i < 4; ++i) {
        const int row = m0 + tm + i;
        if (row < M) {
            float4 o = make_float4(acc[i][0], acc[i][1], acc[i][2], acc[i][3]);
            *(float4*)(C + (size_t)row * N + n0 + tn) = o;
        }
    }
}

// ---------------------------------------------------------------------------
// Epilogue 1: h[i,:] = relu(BN(l2norm(h[i,:] + b2_1)))  over DH=256 columns.
// ---------------------------------------------------------------------------
__global__ __launch_bounds__(256) void epilogue1_kernel(
    float* __restrict__ h, const float* __restrict__ bias,
    const float* __restrict__ gamma, const float* __restrict__ beta,
    const float* __restrict__ mean, const float* __restrict__ var, int n)
{
    const int w = (blockIdx.x * 256 + threadIdx.x) >> 6;
    const int lane = threadIdx.x & 63;
    if (w >= n) return;
    float* row = h + (size_t)w * DH_;
    const int c = lane << 2;

    float4 v = *(float4*)(row + c);
    const float4 bb = *(const float4*)(bias + c);
    v.x += bb.x; v.y += bb.y; v.z += bb.z; v.w += bb.w;

    float ss = v.x * v.x + v.y * v.y + v.z * v.z + v.w * v.w;
    #pragma unroll
    for (int o = 32; o > 0; o >>= 1) ss += __shfl_xor(ss, o);
    const float inv = 1.0f / fmaxf(sqrtf(ss), 1e-12f);

    const float4 g  = *(const float4*)(gamma + c);
    const float4 be = *(const float4*)(beta + c);
    const float4 mn = *(const float4*)(mean + c);
    const float4 vr = *(const float4*)(var + c);

    v.x = fmaxf(g.x * (v.x * inv - mn.x) * rsqrtf(vr.x + 1e-5f) + be.x, 0.f);
    v.y = fmaxf(g.y * (v.y * inv - mn.y) * rsqrtf(vr.y + 1e-5f) + be.y, 0.f);
    v.z = fmaxf(g.z * (v.z * inv - mn.z) * rsqrtf(vr.z + 1e-5f) + be.z, 0.f);
    v.w = fmaxf(g.w * (v.w * inv - mn.w) * rsqrtf(vr.w + 1e-5f) + be.w, 0.f);
    *(float4*)(row + c) = v;
}

// ---------------------------------------------------------------------------
// Epilogue 2: out[i,:] = l2norm(out[i,:] + b2_2)  over DOUT=128 columns.
// ---------------------------------------------------------------------------
__global__ __launch_bounds__(256) void epilogue2_kernel(
    float* __restrict__ out, const float* __restrict__ bias, int n)
{
    const int w = (blockIdx.x * 256 + threadIdx.x) >> 6;
    const int lane = threadIdx.x & 63;
    if (w >= n) return;
    float* row = out + (size_t)w * DOUT_;
    const int c = lane << 1;

    float2 v = *(float2*)(row + c);
    const float2 bb = *(const float2*)(bias + c);
    v.x += bb.x; v.y += bb.y;

    float ss = v.x * v.x + v.y * v.y;
    #pragma unroll
    for (int o = 32; o > 0; o >>= 1) ss += __shfl_xor(ss, o);
    const float inv = 1.0f / fmaxf(sqrtf(ss), 1e-12f);

    v.x *= inv; v.y *= inv;
    *(float2*)(row + c) = v;
}

// ---------------------------------------------------------------------------
extern "C" void kernel_launch(void* const* d_in, const int* in_sizes, int n_in,
                              void* d_out, int out_size, void* d_ws, size_t ws_size,
                              hipStream_t stream)
{
    const float* x     = (const float*)d_in[0];
    const int*   src1  = (const int*)d_in[1];
    const int*   dst1  = (const int*)d_in[2];
    const int*   src2  = (const int*)d_in[3];
    const int*   dst2  = (const int*)d_in[4];
    const float* W1_1  = (const float*)d_in[7];
    const float* W2_1  = (const float*)d_in[8];
    const float* b2_1  = (const float*)d_in[9];
    const float* gamma1= (const float*)d_in[10];
    const float* beta1 = (const float*)d_in[11];
    const float* mean1 = (const float*)d_in[12];
    const float* var1  = (const float*)d_in[13];
    const float* W1_2  = (const float*)d_in[14];
    const float* W2_2  = (const float*)d_in[15];
    const float* b2_2  = (const float*)d_in[16];
    float* out = (float*)d_out;

    const int E1 = in_sizes[1];
    const int E2 = in_sizes[3];
    const int n1 = N1C;
    const int n2 = N2C;

    // Workspace layout (floats), with lifetime-based aliasing:
    //   agg1 [n1*DIN] | agg2 [n2*DH] | h [n1*DH]
    //   esrc1 aliases h       (dead before GEMM1 writes h)
    //   off1/pos1 alias agg2  (dead before gather2 writes agg2)
    //   esrc2/off2/pos2 alias agg1 (written after GEMM1 last reads agg1)
    float* ws   = (float*)d_ws;
    float* agg1 = ws;                                   // 12.8M floats
    float* agg2 = agg1 + (size_t)n1 * DIN_;             // 5.12M floats
    float* h    = agg2 + (size_t)n2 * DH_;              // 25.6M floats

    int* esrc1 = (int*)h;                               // E1 ints
    int* off1  = (int*)agg2;                            // n1+1 ints
    int* pos1  = off1 + (n1 + 1);                       // n1+1 ints

    int* esrc2 = (int*)agg1;                            // E2 ints
    int* off2  = esrc2 + E2;                            // n2+1 ints
    int* pos2  = off2 + (n2 + 1);                       // n2+1 ints

    // ================= Layer 1 =================
    // CSR build for graph 1
    hipMemsetAsync(pos1, 0, (size_t)n1 * sizeof(int), stream);
    hist_kernel<<<(E1 + 255) / 256, 256, 0, stream>>>(dst1, pos1, E1);
    exscan_kernel<<<1, 1024, 0, stream>>>(pos1, off1, pos1, n1);
    scatter_edges_kernel<<<(E1 + 255) / 256, 256, 0, stream>>>(src1, dst1, pos1, esrc1, E1);

    // agg1 = segment_mean(x[src1] by dst1)
    gather_mean_128<<<(n1 + 3) / 4, 256, 0, stream>>>(x, off1, esrc1, agg1, n1);

    // h = x[:n1] @ W1_1^T + agg1 @ W2_1^T
    {
        dim3 grid((n1 + BM - 1) / BM, DH_ / BN);
        gemm_dual_kernel<<<grid, 256, 0, stream>>>(x, W1_1, agg1, W2_1, h, n1, DH_, DIN_);
    }

    // bias, l2norm, BN(eval), ReLU
    epilogue1_kernel<<<(n1 + 3) / 4, 256, 0, stream>>>(h, b2_1, gamma1, beta1, mean1, var1, n1);

    // ================= Layer 2 =================
    // CSR build for graph 2 (esrc2 aliases agg1 — safe after GEMM1)
    hipMemsetAsync(pos2, 0, (size_t)n2 * sizeof(int), stream);
    hist_kernel<<<(E2 + 255) / 256, 256, 0, stream>>>(dst2, pos2, E2);
    exscan_kernel<<<1, 1024, 0, stream>>>(pos2, off2, pos2, n2);
    scatter_edges_kernel<<<(E2 + 255) / 256, 256, 0, stream>>>(src2, dst2, pos2, esrc2, E2);

    // agg2 = segment_mean(h[src2] by dst2)
    gather_mean_256<<<(n2 + 3) / 4, 256, 0, stream>>>(h, off2, esrc2, agg2, n2);

    // out = h[:n2] @ W1_2^T + agg2 @ W2_2^T
    {
        dim3 grid((n2 + BM - 1) / BM, DOUT_ / BN);
        gemm_dual_kernel<<<grid, 256, 0, stream>>>(h, W1_2, agg2, W2_2, out, n2, DOUT_, DH_);
    }

    // bias, l2norm
    epilogue2_kernel<<<(n2 + 3) / 4, 256, 0, stream>>>(out, b2_2, n2);
}

// Round 3
// 963.022 us; speedup vs baseline: 4.6278x; 1.2038x over previous
//
#include <hip/hip_runtime.h>
#include <hip/hip_bf16.h>

// Problem constants (fixed in the reference module)
#define N1C  100000
#define N2C  20000
#define DIN_ 128
#define DH_  256
#define DOUT_ 128

typedef unsigned short ushort_t;
typedef unsigned int   uint_t;
typedef __attribute__((ext_vector_type(8))) short bf16x8;
typedef __attribute__((ext_vector_type(4))) float f32x4;

__device__ __forceinline__ float bf2f(ushort_t u) {
    return __uint_as_float(((uint_t)u) << 16);
}
__device__ __forceinline__ ushort_t f2bf(float f) {
    // round-to-nearest-even bf16
    uint_t x = __float_as_uint(f);
    x += 0x7fffu + ((x >> 16) & 1u);
    return (ushort_t)(x >> 16);
}

// ---------------------------------------------------------------------------
// f32 -> bf16 bulk conversion: 8 elements per thread (2x float4 in, 16 B out)
// ---------------------------------------------------------------------------
__global__ __launch_bounds__(256) void convert_x_kernel(
    const float* __restrict__ src, ushort_t* __restrict__ dst, long long n8)
{
    const long long t = (long long)blockIdx.x * 256 + threadIdx.x;
    if (t >= n8) return;
    const float4 v0 = *(const float4*)(src + t * 8);
    const float4 v1 = *(const float4*)(src + t * 8 + 4);
    uint4 o;
    o.x = (uint_t)f2bf(v0.x) | ((uint_t)f2bf(v0.y) << 16);
    o.y = (uint_t)f2bf(v0.z) | ((uint_t)f2bf(v0.w) << 16);
    o.z = (uint_t)f2bf(v1.x) | ((uint_t)f2bf(v1.y) << 16);
    o.w = (uint_t)f2bf(v1.z) | ((uint_t)f2bf(v1.w) << 16);
    *(uint4*)(dst + t * 8) = o;
}

// ---------------------------------------------------------------------------
// Convert the 4 weight matrices (each 32768 elems) into one bf16 buffer.
// 16384 threads, 8 elems each; mat id is wave-uniform (4096 threads/mat).
// ---------------------------------------------------------------------------
__global__ __launch_bounds__(256) void convert_weights_kernel(
    const float* __restrict__ w0, const float* __restrict__ w1,
    const float* __restrict__ w2, const float* __restrict__ w3,
    ushort_t* __restrict__ dst)
{
    const int t = blockIdx.x * 256 + threadIdx.x;
    if (t >= 16384) return;
    const int mat = t >> 12;                 // 0..3
    const long long idx = (long long)(t & 4095) * 8;
    const float* src = (mat == 0) ? w0 : (mat == 1) ? w1 : (mat == 2) ? w2 : w3;
    const float4 v0 = *(const float4*)(src + idx);
    const float4 v1 = *(const float4*)(src + idx + 4);
    uint4 o;
    o.x = (uint_t)f2bf(v0.x) | ((uint_t)f2bf(v0.y) << 16);
    o.y = (uint_t)f2bf(v0.z) | ((uint_t)f2bf(v0.w) << 16);
    o.z = (uint_t)f2bf(v1.x) | ((uint_t)f2bf(v1.y) << 16);
    o.w = (uint_t)f2bf(v1.z) | ((uint_t)f2bf(v1.w) << 16);
    *(uint4*)(dst + (long long)mat * 32768 + idx) = o;
}

// ---------------------------------------------------------------------------
// CSR build step 1: histogram of dst
// ---------------------------------------------------------------------------
__global__ __launch_bounds__(256) void hist_kernel(
    const int* __restrict__ dst, int* __restrict__ cnt, int E)
{
    const int e = blockIdx.x * 256 + threadIdx.x;
    if (e < E) atomicAdd(&cnt[dst[e]], 1);
}

// ---------------------------------------------------------------------------
// CSR build step 2: exclusive scan (single block, 1024 threads)
// ---------------------------------------------------------------------------
__global__ __launch_bounds__(1024) void exscan_kernel(
    const int* __restrict__ cnt, int* __restrict__ off,
    int* __restrict__ cursor, int n)
{
    __shared__ int wsum[16];
    __shared__ int woff[16];
    __shared__ int s_carry;
    __shared__ int s_total;
    const int lane = threadIdx.x & 63;
    const int wid  = threadIdx.x >> 6;
    if (threadIdx.x == 0) s_carry = 0;
    __syncthreads();
    for (int base = 0; base < n; base += 1024) {
        const int i = base + (int)threadIdx.x;
        const int v = (i < n) ? cnt[i] : 0;
        int s = v;
        #pragma unroll
        for (int o = 1; o < 64; o <<= 1) {
            int t = __shfl_up(s, (unsigned)o);
            if (lane >= o) s += t;
        }
        if (lane == 63) wsum[wid] = s;
        __syncthreads();
        if (wid == 0) {
            int ws = (lane < 16) ? wsum[lane] : 0;
            #pragma unroll
            for (int o = 1; o < 16; o <<= 1) {
                int t = __shfl_up(ws, (unsigned)o);
                if (lane >= o) ws += t;
            }
            if (lane < 16) woff[lane] = ws;
            if (lane == 15) s_total = ws;
        }
        __syncthreads();
        const int carry   = s_carry;
        const int woffset = (wid > 0) ? woff[wid - 1] : 0;
        const int exc = carry + woffset + s - v;
        if (i < n) { off[i] = exc; cursor[i] = exc; }
        __syncthreads();
        if (threadIdx.x == 0) s_carry = carry + s_total;
        __syncthreads();
    }
    if (threadIdx.x == 0) off[n] = s_carry;
}

// ---------------------------------------------------------------------------
// CSR build step 3: scatter edge source ids into dst-sorted order
// ---------------------------------------------------------------------------
__global__ __launch_bounds__(256) void scatter_edges_kernel(
    const int* __restrict__ src, const int* __restrict__ dst,
    int* __restrict__ cursor, int* __restrict__ esrc, int E)
{
    const int e = blockIdx.x * 256 + threadIdx.x;
    if (e < E) {
        const int p = atomicAdd(&cursor[dst[e]], 1);
        esrc[p] = src[e];
    }
}

// ---------------------------------------------------------------------------
// Gather segment-mean over bf16 table, D=128: one wave/row, 2 cols/lane.
// ---------------------------------------------------------------------------
__global__ __launch_bounds__(256) void gather_mean_128_bf16(
    const ushort_t* __restrict__ X, const int* __restrict__ off,
    const int* __restrict__ esrc, ushort_t* __restrict__ agg, int n)
{
    const int w = (blockIdx.x * 256 + threadIdx.x) >> 6;
    const int lane = threadIdx.x & 63;
    if (w >= n) return;
    const int beg = off[w], end = off[w + 1];
    const int c = lane << 1;
    float ax = 0.f, ay = 0.f;
    int e = beg;
    for (; e + 1 < end; e += 2) {
        const int s0 = esrc[e], s1 = esrc[e + 1];
        const uint_t u0 = *(const uint_t*)(X + (size_t)s0 * DIN_ + c);
        const uint_t u1 = *(const uint_t*)(X + (size_t)s1 * DIN_ + c);
        ax += bf2f((ushort_t)u0) + bf2f((ushort_t)u1);
        ay += bf2f((ushort_t)(u0 >> 16)) + bf2f((ushort_t)(u1 >> 16));
    }
    if (e < end) {
        const uint_t u0 = *(const uint_t*)(X + (size_t)esrc[e] * DIN_ + c);
        ax += bf2f((ushort_t)u0);
        ay += bf2f((ushort_t)(u0 >> 16));
    }
    const float r = 1.0f / fmaxf((float)(end - beg), 1.0f);
    const uint_t o = (uint_t)f2bf(ax * r) | ((uint_t)f2bf(ay * r) << 16);
    *(uint_t*)(agg + (size_t)w * DIN_ + c) = o;
}

// ---------------------------------------------------------------------------
// Gather segment-mean over bf16 table, D=256: one wave/row, 4 cols/lane.
// ---------------------------------------------------------------------------
__global__ __launch_bounds__(256) void gather_mean_256_bf16(
    const ushort_t* __restrict__ X, const int* __restrict__ off,
    const int* __restrict__ esrc, ushort_t* __restrict__ agg, int n)
{
    const int w = (blockIdx.x * 256 + threadIdx.x) >> 6;
    const int lane = threadIdx.x & 63;
    if (w >= n) return;
    const int beg = off[w], end = off[w + 1];
    const int c = lane << 2;
    float a0 = 0.f, a1 = 0.f, a2 = 0.f, a3 = 0.f;
    int e = beg;
    for (; e + 1 < end; e += 2) {
        const int s0 = esrc[e], s1 = esrc[e + 1];
        const uint2 u0 = *(const uint2*)(X + (size_t)s0 * DH_ + c);
        const uint2 u1 = *(const uint2*)(X + (size_t)s1 * DH_ + c);
        a0 += bf2f((ushort_t)u0.x) + bf2f((ushort_t)u1.x);
        a1 += bf2f((ushort_t)(u0.x >> 16)) + bf2f((ushort_t)(u1.x >> 16));
        a2 += bf2f((ushort_t)u0.y) + bf2f((ushort_t)u1.y);
        a3 += bf2f((ushort_t)(u0.y >> 16)) + bf2f((ushort_t)(u1.y >> 16));
    }
    if (e < end) {
        const uint2 u0 = *(const uint2*)(X + (size_t)esrc[e] * DH_ + c);
        a0 += bf2f((ushort_t)u0.x);
        a1 += bf2f((ushort_t)(u0.x >> 16));
        a2 += bf2f((ushort_t)u0.y);
        a3 += bf2f((ushort_t)(u0.y >> 16));
    }
    const float r = 1.0f / fmaxf((float)(end - beg), 1.0f);
    uint2 o;
    o.x = (uint_t)f2bf(a0 * r) | ((uint_t)f2bf(a1 * r) << 16);
    o.y = (uint_t)f2bf(a2 * r) | ((uint_t)f2bf(a3 * r) << 16);
    *(uint2*)(agg + (size_t)w * DH_ + c) = o;
}

// ---------------------------------------------------------------------------
// Dual-A bf16 MFMA GEMM: C[M,N] = A1 @ B1^T + A2 @ B2^T
//   A1,A2: [M,K] bf16 row-major; B1,B2: [N,K] bf16 row-major.
// 256 threads / 4 waves; 128x128 tile; per wave 64x64 via 4x4 of 16x16x32.
// LDS rows padded to 40 bf16 (80 B): bank base 20*m%32 covers all 32 banks
// over 8 rows -> only the free 2-way aliasing on ds_read_b128.
// ---------------------------------------------------------------------------
template<bool OUT_BF16>
__global__ __launch_bounds__(256) void gemm_dual_mfma(
    const ushort_t* __restrict__ A1, const ushort_t* __restrict__ B1,
    const ushort_t* __restrict__ A2, const ushort_t* __restrict__ B2,
    void* __restrict__ Cout, int M, int N, int K)
{
    __shared__ ushort_t As[128][40];
    __shared__ ushort_t Bs[128][40];

    const int tid = threadIdx.x;
    const int m0 = blockIdx.x * 128;
    const int n0 = blockIdx.y * 128;

    // staging map: thread -> (row, 8-elem chunk {q, q+2})
    const int lr = tid >> 1;           // 0..127
    const int lq = (tid & 1) * 8;      // elem offset 0 or 8

    // compute map
    const int wid  = tid >> 6;
    const int lane = tid & 63;
    const int lm   = lane & 15;
    const int lqq  = lane >> 4;        // 0..3
    const int wrow = (wid >> 1) * 64;
    const int wcol = (wid & 1) * 64;

    const f32x4 fzero = {0.f, 0.f, 0.f, 0.f};
    f32x4 acc[4][4];
    #pragma unroll
    for (int i = 0; i < 4; ++i)
        #pragma unroll
        for (int j = 0; j < 4; ++j) acc[i][j] = fzero;

    const bool arow_ok = (m0 + lr) < M;

    for (int phase = 0; phase < 2; ++phase) {
        const ushort_t* __restrict__ A = phase ? A2 : A1;
        const ushort_t* __restrict__ B = phase ? B2 : B1;
        const ushort_t* Ap = A + (size_t)(m0 + lr) * K + lq;
        const ushort_t* Bp = B + (size_t)(n0 + lr) * K + lq;

        for (int k0 = 0; k0 < K; k0 += 32) {
            uint4 a0 = {0, 0, 0, 0}, a1 = {0, 0, 0, 0};
            if (arow_ok) {
                a0 = *(const uint4*)(Ap + k0);
                a1 = *(const uint4*)(Ap + k0 + 16);
            }
            const uint4 b0 = *(const uint4*)(Bp + k0);
            const uint4 b1 = *(const uint4*)(Bp + k0 + 16);

            __syncthreads();   // previous iteration's LDS reads done
            *(uint4*)&As[lr][lq]      = a0;
            *(uint4*)&As[lr][lq + 16] = a1;
            *(uint4*)&Bs[lr][lq]      = b0;
            *(uint4*)&Bs[lr][lq + 16] = b1;
            __syncthreads();

            bf16x8 af[4], bfr[4];
            #pragma unroll
            for (int i = 0; i < 4; ++i)
                af[i] = *(const bf16x8*)&As[wrow + i * 16 + lm][lqq * 8];
            #pragma unroll
            for (int j = 0; j < 4; ++j)
                bfr[j] = *(const bf16x8*)&Bs[wcol + j * 16 + lm][lqq * 8];

            #pragma unroll
            for (int i = 0; i < 4; ++i)
                #pragma unroll
                for (int j = 0; j < 4; ++j)
                    acc[i][j] = __builtin_amdgcn_mfma_f32_16x16x32_bf16(
                        af[i], bfr[j], acc[i][j], 0, 0, 0);
        }
    }

    // store: C/D layout col=lane&15, row=(lane>>4)*4+reg
    float*    Cf = (float*)Cout;
    ushort_t* Cb = (ushort_t*)Cout;
    #pragma unroll
    for (int i = 0; i < 4; ++i) {
        #pragma unroll
        for (int r = 0; r < 4; ++r) {
            const int row = m0 + wrow + i * 16 + lqq * 4 + r;
            if (row < M) {
                const size_t base = (size_t)row * N + n0 + wcol + lm;
                #pragma unroll
                for (int j = 0; j < 4; ++j) {
                    const float v = acc[i][j][r];
                    if (OUT_BF16) Cb[base + j * 16] = f2bf(v);
                    else          Cf[base + j * 16] = v;
                }
            }
        }
    }
}

// ---------------------------------------------------------------------------
// Epilogue 1 (bf16 h): h = relu(BN(l2norm(h + b2_1))); one wave/row, 4/lane.
// ---------------------------------------------------------------------------
__global__ __launch_bounds__(256) void epilogue1_bf16(
    ushort_t* __restrict__ h, const float* __restrict__ bias,
    const float* __restrict__ gamma, const float* __restrict__ beta,
    const float* __restrict__ mean, const float* __restrict__ var, int n)
{
    const int w = (blockIdx.x * 256 + threadIdx.x) >> 6;
    const int lane = threadIdx.x & 63;
    if (w >= n) return;
    ushort_t* row = h + (size_t)w * DH_;
    const int c = lane << 2;

    const uint2 u = *(const uint2*)(row + c);
    const float4 bb = *(const float4*)(bias + c);
    float v0 = bf2f((ushort_t)u.x)         + bb.x;
    float v1 = bf2f((ushort_t)(u.x >> 16)) + bb.y;
    float v2 = bf2f((ushort_t)u.y)         + bb.z;
    float v3 = bf2f((ushort_t)(u.y >> 16)) + bb.w;

    float ss = v0 * v0 + v1 * v1 + v2 * v2 + v3 * v3;
    #pragma unroll
    for (int o = 32; o > 0; o >>= 1) ss += __shfl_xor(ss, o);
    const float inv = 1.0f / fmaxf(sqrtf(ss), 1e-12f);

    const float4 g  = *(const float4*)(gamma + c);
    const float4 be = *(const float4*)(beta + c);
    const float4 mn = *(const float4*)(mean + c);
    const float4 vr = *(const float4*)(var + c);

    v0 = fmaxf(g.x * (v0 * inv - mn.x) * rsqrtf(vr.x + 1e-5f) + be.x, 0.f);
    v1 = fmaxf(g.y * (v1 * inv - mn.y) * rsqrtf(vr.y + 1e-5f) + be.y, 0.f);
    v2 = fmaxf(g.z * (v2 * inv - mn.z) * rsqrtf(vr.z + 1e-5f) + be.z, 0.f);
    v3 = fmaxf(g.w * (v3 * inv - mn.w) * rsqrtf(vr.w + 1e-5f) + be.w, 0.f);

    uint2 o;
    o.x = (uint_t)f2bf(v0) | ((uint_t)f2bf(v1) << 16);
    o.y = (uint_t)f2bf(v2) | ((uint_t)f2bf(v3) << 16);
    *(uint2*)(row + c) = o;
}

// ---------------------------------------------------------------------------
// Epilogue 2 (f32 out): out = l2norm(out + b2_2); one wave/row, 2/lane.
// ---------------------------------------------------------------------------
__global__ __launch_bounds__(256) void epilogue2_kernel(
    float* __restrict__ out, const float* __restrict__ bias, int n)
{
    const int w = (blockIdx.x * 256 + threadIdx.x) >> 6;
    const int lane = threadIdx.x & 63;
    if (w >= n) return;
    float* row = out + (size_t)w * DOUT_;
    const int c = lane << 1;

    float2 v = *(float2*)(row + c);
    const float2 bb = *(const float2*)(bias + c);
    v.x += bb.x; v.y += bb.y;

    float ss = v.x * v.x + v.y * v.y;
    #pragma unroll
    for (int o = 32; o > 0; o >>= 1) ss += __shfl_xor(ss, o);
    const float inv = 1.0f / fmaxf(sqrtf(ss), 1e-12f);

    v.x *= inv; v.y *= inv;
    *(float2*)(row + c) = v;
}

// ---------------------------------------------------------------------------
extern "C" void kernel_launch(void* const* d_in, const int* in_sizes, int n_in,
                              void* d_out, int out_size, void* d_ws, size_t ws_size,
                              hipStream_t stream)
{
    const float* x     = (const float*)d_in[0];
    const int*   src1  = (const int*)d_in[1];
    const int*   dst1  = (const int*)d_in[2];
    const int*   src2  = (const int*)d_in[3];
    const int*   dst2  = (const int*)d_in[4];
    const float* W1_1  = (const float*)d_in[7];
    const float* W2_1  = (const float*)d_in[8];
    const float* b2_1  = (const float*)d_in[9];
    const float* gamma1= (const float*)d_in[10];
    const float* beta1 = (const float*)d_in[11];
    const float* mean1 = (const float*)d_in[12];
    const float* var1  = (const float*)d_in[13];
    const float* W1_2  = (const float*)d_in[14];
    const float* W2_2  = (const float*)d_in[15];
    const float* b2_2  = (const float*)d_in[16];
    float* out = (float*)d_out;

    const int E1 = in_sizes[1];
    const int E2 = in_sizes[3];
    const int n1 = N1C;
    const int n2 = N2C;

    // Workspace layout (byte offsets), lifetime-aliased; peak ~161 MB:
    //   [0, 128e6)          xb: bf16 x, 500k x 128
    //     h      = +25.6e6  (51.2e6 B; GEMM1 reads xb rows < n1 = bytes < 25.6e6)
    //     esrc2  = +80.0e6  (dead zone of xb after GEMM1)
    //     off2   = +81.6e6, pos2 = +81.76e6
    //     agg2   = +90.0e6  (10.24e6 B)
    //   [128e6, 153.6e6)    agg1 bf16
    //   [153.6e6, 160e6)    esrc1
    //   [160e6, ...]        off1, pos1
    //   [160.804e6, ...]    wb: bf16 weights (4 x 32768 elems)
    char* wsb = (char*)d_ws;
    ushort_t* xb    = (ushort_t*)wsb;
    ushort_t* h     = (ushort_t*)(wsb + 25600000);
    int*      esrc2 = (int*)(wsb + 80000000);
    int*      off2  = (int*)(wsb + 81600000);
    int*      pos2  = (int*)(wsb + 81760000);
    ushort_t* agg2  = (ushort_t*)(wsb + 90000000);
    ushort_t* agg1  = (ushort_t*)(wsb + 128000000);
    int*      esrc1 = (int*)(wsb + 153600000);
    int*      off1  = (int*)(wsb + 160000000);
    int*      pos1  = (int*)(wsb + 160404000);
    ushort_t* wb    = (ushort_t*)(wsb + 160804000);
    ushort_t* w11b = wb;
    ushort_t* w21b = wb + 32768;
    ushort_t* w12b = wb + 65536;
    ushort_t* w22b = wb + 98304;

    // --- x -> bf16 table (500000*128 elems / 8 per thread) ---
    {
        const long long n8 = (long long)500000 * DIN_ / 8;
        convert_x_kernel<<<(int)((n8 + 255) / 256), 256, 0, stream>>>(x, xb, n8);
    }
    convert_weights_kernel<<<64, 256, 0, stream>>>(W1_1, W2_1, W1_2, W2_2, wb);

    // --- CSR 1 ---
    hipMemsetAsync(pos1, 0, (size_t)n1 * sizeof(int), stream);
    hist_kernel<<<(E1 + 255) / 256, 256, 0, stream>>>(dst1, pos1, E1);
    exscan_kernel<<<1, 1024, 0, stream>>>(pos1, off1, pos1, n1);
    scatter_edges_kernel<<<(E1 + 255) / 256, 256, 0, stream>>>(src1, dst1, pos1, esrc1, E1);

    // --- agg1 = segment_mean(xb[src1] by dst1), bf16 ---
    gather_mean_128_bf16<<<(n1 + 3) / 4, 256, 0, stream>>>(xb, off1, esrc1, agg1, n1);

    // --- GEMM1: h = xb[:n1] @ W1_1^T + agg1 @ W2_1^T  (bf16 out) ---
    {
        dim3 grid((n1 + 127) / 128, DH_ / 128);
        gemm_dual_mfma<true><<<grid, 256, 0, stream>>>(xb, w11b, agg1, w21b, h, n1, DH_, DIN_);
    }

    // --- epilogue 1: bias, l2norm, BN(eval), ReLU (in-place bf16) ---
    epilogue1_bf16<<<(n1 + 3) / 4, 256, 0, stream>>>(h, b2_1, gamma1, beta1, mean1, var1, n1);

    // --- CSR 2 (in xb dead zone) ---
    hipMemsetAsync(pos2, 0, (size_t)n2 * sizeof(int), stream);
    hist_kernel<<<(E2 + 255) / 256, 256, 0, stream>>>(dst2, pos2, E2);
    exscan_kernel<<<1, 1024, 0, stream>>>(pos2, off2, pos2, n2);
    scatter_edges_kernel<<<(E2 + 255) / 256, 256, 0, stream>>>(src2, dst2, pos2, esrc2, E2);

    // --- agg2 = segment_mean(h[src2] by dst2), bf16 ---
    gather_mean_256_bf16<<<(n2 + 3) / 4, 256, 0, stream>>>(h, off2, esrc2, agg2, n2);

    // --- GEMM2: out = h[:n2] @ W1_2^T + agg2 @ W2_2^T  (f32 out) ---
    {
        dim3 grid((n2 + 127) / 128, DOUT_ / 128);
        gemm_dual_mfma<false><<<grid, 256, 0, stream>>>(h, w12b, agg2, w22b, out, n2, DOUT_, DH_);
    }

    // --- epilogue 2: bias, l2norm (f32, in-place on d_out) ---
    epilogue2_kernel<<<(n2 + 3) / 4, 256, 0, stream>>>(out, b2_2, n2);
}

// Round 4
// 814.585 us; speedup vs baseline: 5.4711x; 1.1822x over previous
//
#include <hip/hip_runtime.h>
#include <hip/hip_bf16.h>

// Problem constants (fixed in the reference module)
#define N1C  100000
#define N2C  20000
#define DIN_ 128
#define DH_  256
#define DOUT_ 128
#define CHUNK 4096                 // scan chunk: 256 threads x 16 ints
#define NB1  25                    // ceil(100000/4096) -> padded 102400
#define NB2  5                     // ceil(20000/4096)  -> padded 20480

typedef unsigned short ushort_t;
typedef unsigned int   uint_t;
typedef __attribute__((ext_vector_type(8))) short bf16x8;
typedef __attribute__((ext_vector_type(4))) float f32x4;

__device__ __forceinline__ float bf2f(ushort_t u) {
    return __uint_as_float(((uint_t)u) << 16);
}
__device__ __forceinline__ ushort_t f2bf(float f) {
    uint_t x = __float_as_uint(f);
    x += 0x7fffu + ((x >> 16) & 1u);
    return (ushort_t)(x >> 16);
}

// ---------------------------------------------------------------------------
// f32 -> bf16 bulk conversion: 8 elements per thread
// ---------------------------------------------------------------------------
__global__ __launch_bounds__(256) void convert_x_kernel(
    const float* __restrict__ src, ushort_t* __restrict__ dst, long long n8)
{
    const long long t = (long long)blockIdx.x * 256 + threadIdx.x;
    if (t >= n8) return;
    const float4 v0 = *(const float4*)(src + t * 8);
    const float4 v1 = *(const float4*)(src + t * 8 + 4);
    uint4 o;
    o.x = (uint_t)f2bf(v0.x) | ((uint_t)f2bf(v0.y) << 16);
    o.y = (uint_t)f2bf(v0.z) | ((uint_t)f2bf(v0.w) << 16);
    o.z = (uint_t)f2bf(v1.x) | ((uint_t)f2bf(v1.y) << 16);
    o.w = (uint_t)f2bf(v1.z) | ((uint_t)f2bf(v1.w) << 16);
    *(uint4*)(dst + t * 8) = o;
}

// ---------------------------------------------------------------------------
// Convert the 4 weight matrices (each 32768 elems) into one bf16 buffer.
// ---------------------------------------------------------------------------
__global__ __launch_bounds__(256) void convert_weights_kernel(
    const float* __restrict__ w0, const float* __restrict__ w1,
    const float* __restrict__ w2, const float* __restrict__ w3,
    ushort_t* __restrict__ dst)
{
    const int t = blockIdx.x * 256 + threadIdx.x;
    if (t >= 16384) return;
    const int mat = t >> 12;
    const long long idx = (long long)(t & 4095) * 8;
    const float* src = (mat == 0) ? w0 : (mat == 1) ? w1 : (mat == 2) ? w2 : w3;
    const float4 v0 = *(const float4*)(src + idx);
    const float4 v1 = *(const float4*)(src + idx + 4);
    uint4 o;
    o.x = (uint_t)f2bf(v0.x) | ((uint_t)f2bf(v0.y) << 16);
    o.y = (uint_t)f2bf(v0.z) | ((uint_t)f2bf(v0.w) << 16);
    o.z = (uint_t)f2bf(v1.x) | ((uint_t)f2bf(v1.y) << 16);
    o.w = (uint_t)f2bf(v1.z) | ((uint_t)f2bf(v1.w) << 16);
    *(uint4*)(dst + (long long)mat * 32768 + idx) = o;
}

// ---------------------------------------------------------------------------
// Merged histogram for both graphs
// ---------------------------------------------------------------------------
__global__ __launch_bounds__(256) void hist_both_kernel(
    const int* __restrict__ dst1, int E1, const int* __restrict__ dst2, int E2,
    int* __restrict__ cnt1, int* __restrict__ cnt2)
{
    const int t = blockIdx.x * 256 + threadIdx.x;
    if (t < E1)            atomicAdd(&cnt1[dst1[t]], 1);
    else if (t < E1 + E2)  atomicAdd(&cnt2[dst2[t - E1]], 1);
}

// ---------------------------------------------------------------------------
// Scan phase 1: per-4096-chunk sums. Blocks [0,NB1) -> graph1, rest -> graph2.
// cnt arrays are zero-padded to NB*4096, so no bounds checks.
// ---------------------------------------------------------------------------
__global__ __launch_bounds__(256) void scan_partial_kernel(
    const int* __restrict__ cnt1, int* __restrict__ bsum1,
    const int* __restrict__ cnt2, int* __restrict__ bsum2)
{
    __shared__ int wsum[4];
    const int b = blockIdx.x;
    const int* cnt = (b < NB1) ? cnt1 : cnt2;
    int*     bsum = (b < NB1) ? bsum1 : bsum2;
    const int cb  = (b < NB1) ? b : b - NB1;

    const int4* p = (const int4*)(cnt + (size_t)cb * CHUNK) + threadIdx.x * 4;
    const int4 a = p[0], bq = p[1], c = p[2], d = p[3];
    int s = a.x + a.y + a.z + a.w + bq.x + bq.y + bq.z + bq.w
          + c.x + c.y + c.z + c.w + d.x + d.y + d.z + d.w;
    #pragma unroll
    for (int o = 32; o > 0; o >>= 1) s += __shfl_xor(s, o);
    const int lane = threadIdx.x & 63, wid = threadIdx.x >> 6;
    if (lane == 0) wsum[wid] = s;
    __syncthreads();
    if (threadIdx.x == 0)
        bsum[cb] = wsum[0] + wsum[1] + wsum[2] + wsum[3];
}

// ---------------------------------------------------------------------------
// Scan phase 2: exclusive scan of the (<=64) chunk sums; wave0=g1, wave1=g2.
// ---------------------------------------------------------------------------
__global__ __launch_bounds__(128) void scan_bsums_kernel(
    const int* __restrict__ bsum1, int* __restrict__ boff1,
    const int* __restrict__ bsum2, int* __restrict__ boff2)
{
    const int lane = threadIdx.x & 63;
    const int wid  = threadIdx.x >> 6;
    const int* bs = wid ? bsum2 : bsum1;
    int*       bo = wid ? boff2 : boff1;
    const int  nb = wid ? NB2 : NB1;
    int v = (lane < nb) ? bs[lane] : 0;
    int s = v;
    #pragma unroll
    for (int o = 1; o < 64; o <<= 1) {
        int t = __shfl_up(s, (unsigned)o);
        if (lane >= o) s += t;
    }
    if (lane < nb) bo[lane] = s - v;
}

// ---------------------------------------------------------------------------
// Scan phase 3: per-chunk exclusive scan + chunk offset; writes off and pos.
// off/pos arrays are padded to NB*4096 ints; off[n] lands naturally since the
// padded cnt tail is zero.
// ---------------------------------------------------------------------------
__global__ __launch_bounds__(256) void scan_final_kernel(
    const int* __restrict__ cnt1, const int* __restrict__ boff1,
    int* __restrict__ off1, int* __restrict__ pos1,
    const int* __restrict__ cnt2, const int* __restrict__ boff2,
    int* __restrict__ off2, int* __restrict__ pos2)
{
    __shared__ int wsum[4];
    const int b = blockIdx.x;
    const int* cnt  = (b < NB1) ? cnt1  : cnt2;
    const int* boff = (b < NB1) ? boff1 : boff2;
    int* off = (b < NB1) ? off1 : off2;
    int* pos = (b < NB1) ? pos1 : pos2;
    const int cb = (b < NB1) ? b : b - NB1;

    const size_t base = (size_t)cb * CHUNK + threadIdx.x * 16;
    int v[16];
    {
        const int4* p = (const int4*)(cnt + base);
        int4 q0 = p[0], q1 = p[1], q2 = p[2], q3 = p[3];
        v[0]=q0.x; v[1]=q0.y; v[2]=q0.z; v[3]=q0.w;
        v[4]=q1.x; v[5]=q1.y; v[6]=q1.z; v[7]=q1.w;
        v[8]=q2.x; v[9]=q2.y; v[10]=q2.z; v[11]=q2.w;
        v[12]=q3.x; v[13]=q3.y; v[14]=q3.z; v[15]=q3.w;
    }
    int tsum = 0;
    #pragma unroll
    for (int j = 0; j < 16; ++j) tsum += v[j];

    const int lane = threadIdx.x & 63, wid = threadIdx.x >> 6;
    int s = tsum;
    #pragma unroll
    for (int o = 1; o < 64; o <<= 1) {
        int t = __shfl_up(s, (unsigned)o);
        if (lane >= o) s += t;
    }
    if (lane == 63) wsum[wid] = s;
    __syncthreads();
    int wprefix = 0;
    #pragma unroll
    for (int k = 0; k < 4; ++k) wprefix += (k < wid) ? wsum[k] : 0;

    int run = boff[cb] + wprefix + (s - tsum);
    int o16[16];
    #pragma unroll
    for (int j = 0; j < 16; ++j) { o16[j] = run; run += v[j]; }
    {
        int4* po = (int4*)(off + base);
        int4* pp = (int4*)(pos + base);
        #pragma unroll
        for (int q = 0; q < 4; ++q) {
            int4 w = make_int4(o16[q*4], o16[q*4+1], o16[q*4+2], o16[q*4+3]);
            po[q] = w; pp[q] = w;
        }
    }
}

// ---------------------------------------------------------------------------
// Merged edge scatter for both graphs
// ---------------------------------------------------------------------------
__global__ __launch_bounds__(256) void scatter_both_kernel(
    const int* __restrict__ src1, const int* __restrict__ dst1, int E1,
    const int* __restrict__ src2, const int* __restrict__ dst2, int E2,
    int* __restrict__ pos1, int* __restrict__ esrc1,
    int* __restrict__ pos2, int* __restrict__ esrc2)
{
    const int t = blockIdx.x * 256 + threadIdx.x;
    if (t < E1) {
        const int p = atomicAdd(&pos1[dst1[t]], 1);
        esrc1[p] = src1[t];
    } else if (t < E1 + E2) {
        const int e = t - E1;
        const int p = atomicAdd(&pos2[dst2[e]], 1);
        esrc2[p] = src2[e];
    }
}

// ---------------------------------------------------------------------------
// Gather segment-mean over bf16 table, D=128: one wave/row, 2 cols/lane.
// ---------------------------------------------------------------------------
__global__ __launch_bounds__(256) void gather_mean_128_bf16(
    const ushort_t* __restrict__ X, const int* __restrict__ off,
    const int* __restrict__ esrc, ushort_t* __restrict__ agg, int n)
{
    const int w = (blockIdx.x * 256 + threadIdx.x) >> 6;
    const int lane = threadIdx.x & 63;
    if (w >= n) return;
    const int beg = off[w], end = off[w + 1];
    const int c = lane << 1;
    float ax = 0.f, ay = 0.f;
    int e = beg;
    for (; e + 3 < end; e += 4) {
        const int s0 = esrc[e], s1 = esrc[e+1], s2 = esrc[e+2], s3 = esrc[e+3];
        const uint_t u0 = *(const uint_t*)(X + (size_t)s0 * DIN_ + c);
        const uint_t u1 = *(const uint_t*)(X + (size_t)s1 * DIN_ + c);
        const uint_t u2 = *(const uint_t*)(X + (size_t)s2 * DIN_ + c);
        const uint_t u3 = *(const uint_t*)(X + (size_t)s3 * DIN_ + c);
        ax += bf2f((ushort_t)u0) + bf2f((ushort_t)u1)
            + bf2f((ushort_t)u2) + bf2f((ushort_t)u3);
        ay += bf2f((ushort_t)(u0 >> 16)) + bf2f((ushort_t)(u1 >> 16))
            + bf2f((ushort_t)(u2 >> 16)) + bf2f((ushort_t)(u3 >> 16));
    }
    for (; e < end; ++e) {
        const uint_t u0 = *(const uint_t*)(X + (size_t)esrc[e] * DIN_ + c);
        ax += bf2f((ushort_t)u0);
        ay += bf2f((ushort_t)(u0 >> 16));
    }
    const float r = 1.0f / fmaxf((float)(end - beg), 1.0f);
    const uint_t o = (uint_t)f2bf(ax * r) | ((uint_t)f2bf(ay * r) << 16);
    *(uint_t*)(agg + (size_t)w * DIN_ + c) = o;
}

// ---------------------------------------------------------------------------
// Gather segment-mean over bf16 table, D=256: one wave/row, 4 cols/lane.
// ---------------------------------------------------------------------------
__global__ __launch_bounds__(256) void gather_mean_256_bf16(
    const ushort_t* __restrict__ X, const int* __restrict__ off,
    const int* __restrict__ esrc, ushort_t* __restrict__ agg, int n)
{
    const int w = (blockIdx.x * 256 + threadIdx.x) >> 6;
    const int lane = threadIdx.x & 63;
    if (w >= n) return;
    const int beg = off[w], end = off[w + 1];
    const int c = lane << 2;
    float a0 = 0.f, a1 = 0.f, a2 = 0.f, a3 = 0.f;
    int e = beg;
    for (; e + 3 < end; e += 4) {
        const int s0 = esrc[e], s1 = esrc[e+1], s2 = esrc[e+2], s3 = esrc[e+3];
        const uint2 u0 = *(const uint2*)(X + (size_t)s0 * DH_ + c);
        const uint2 u1 = *(const uint2*)(X + (size_t)s1 * DH_ + c);
        const uint2 u2 = *(const uint2*)(X + (size_t)s2 * DH_ + c);
        const uint2 u3 = *(const uint2*)(X + (size_t)s3 * DH_ + c);
        a0 += bf2f((ushort_t)u0.x) + bf2f((ushort_t)u1.x)
            + bf2f((ushort_t)u2.x) + bf2f((ushort_t)u3.x);
        a1 += bf2f((ushort_t)(u0.x >> 16)) + bf2f((ushort_t)(u1.x >> 16))
            + bf2f((ushort_t)(u2.x >> 16)) + bf2f((ushort_t)(u3.x >> 16));
        a2 += bf2f((ushort_t)u0.y) + bf2f((ushort_t)u1.y)
            + bf2f((ushort_t)u2.y) + bf2f((ushort_t)u3.y);
        a3 += bf2f((ushort_t)(u0.y >> 16)) + bf2f((ushort_t)(u1.y >> 16))
            + bf2f((ushort_t)(u2.y >> 16)) + bf2f((ushort_t)(u3.y >> 16));
    }
    for (; e < end; ++e) {
        const uint2 u0 = *(const uint2*)(X + (size_t)esrc[e] * DH_ + c);
        a0 += bf2f((ushort_t)u0.x);
        a1 += bf2f((ushort_t)(u0.x >> 16));
        a2 += bf2f((ushort_t)u0.y);
        a3 += bf2f((ushort_t)(u0.y >> 16));
    }
    const float r = 1.0f / fmaxf((float)(end - beg), 1.0f);
    uint2 o;
    o.x = (uint_t)f2bf(a0 * r) | ((uint_t)f2bf(a1 * r) << 16);
    o.y = (uint_t)f2bf(a2 * r) | ((uint_t)f2bf(a3 * r) << 16);
    *(uint2*)(agg + (size_t)w * DH_ + c) = o;
}

// ---------------------------------------------------------------------------
// Dual-A bf16 MFMA GEMM: C[M,N] = A1 @ B1^T + A2 @ B2^T (unchanged, verified)
// ---------------------------------------------------------------------------
template<bool OUT_BF16>
__global__ __launch_bounds__(256) void gemm_dual_mfma(
    const ushort_t* __restrict__ A1, const ushort_t* __restrict__ B1,
    const ushort_t* __restrict__ A2, const ushort_t* __restrict__ B2,
    void* __restrict__ Cout, int M, int N, int K)
{
    __shared__ ushort_t As[128][40];
    __shared__ ushort_t Bs[128][40];

    const int tid = threadIdx.x;
    const int m0 = blockIdx.x * 128;
    const int n0 = blockIdx.y * 128;

    const int lr = tid >> 1;
    const int lq = (tid & 1) * 8;

    const int wid  = tid >> 6;
    const int lane = tid & 63;
    const int lm   = lane & 15;
    const int lqq  = lane >> 4;
    const int wrow = (wid >> 1) * 64;
    const int wcol = (wid & 1) * 64;

    const f32x4 fzero = {0.f, 0.f, 0.f, 0.f};
    f32x4 acc[4][4];
    #pragma unroll
    for (int i = 0; i < 4; ++i)
        #pragma unroll
        for (int j = 0; j < 4; ++j) acc[i][j] = fzero;

    const bool arow_ok = (m0 + lr) < M;

    for (int phase = 0; phase < 2; ++phase) {
        const ushort_t* __restrict__ A = phase ? A2 : A1;
        const ushort_t* __restrict__ B = phase ? B2 : B1;
        const ushort_t* Ap = A + (size_t)(m0 + lr) * K + lq;
        const ushort_t* Bp = B + (size_t)(n0 + lr) * K + lq;

        for (int k0 = 0; k0 < K; k0 += 32) {
            uint4 a0 = {0, 0, 0, 0}, a1 = {0, 0, 0, 0};
            if (arow_ok) {
                a0 = *(const uint4*)(Ap + k0);
                a1 = *(const uint4*)(Ap + k0 + 16);
            }
            const uint4 b0 = *(const uint4*)(Bp + k0);
            const uint4 b1 = *(const uint4*)(Bp + k0 + 16);

            __syncthreads();
            *(uint4*)&As[lr][lq]      = a0;
            *(uint4*)&As[lr][lq + 16] = a1;
            *(uint4*)&Bs[lr][lq]      = b0;
            *(uint4*)&Bs[lr][lq + 16] = b1;
            __syncthreads();

            bf16x8 af[4], bfr[4];
            #pragma unroll
            for (int i = 0; i < 4; ++i)
                af[i] = *(const bf16x8*)&As[wrow + i * 16 + lm][lqq * 8];
            #pragma unroll
            for (int j = 0; j < 4; ++j)
                bfr[j] = *(const bf16x8*)&Bs[wcol + j * 16 + lm][lqq * 8];

            #pragma unroll
            for (int i = 0; i < 4; ++i)
                #pragma unroll
                for (int j = 0; j < 4; ++j)
                    acc[i][j] = __builtin_amdgcn_mfma_f32_16x16x32_bf16(
                        af[i], bfr[j], acc[i][j], 0, 0, 0);
        }
    }

    float*    Cf = (float*)Cout;
    ushort_t* Cb = (ushort_t*)Cout;
    #pragma unroll
    for (int i = 0; i < 4; ++i) {
        #pragma unroll
        for (int r = 0; r < 4; ++r) {
            const int row = m0 + wrow + i * 16 + lqq * 4 + r;
            if (row < M) {
                const size_t base = (size_t)row * N + n0 + wcol + lm;
                #pragma unroll
                for (int j = 0; j < 4; ++j) {
                    const float v = acc[i][j][r];
                    if (OUT_BF16) Cb[base + j * 16] = f2bf(v);
                    else          Cf[base + j * 16] = v;
                }
            }
        }
    }
}

// ---------------------------------------------------------------------------
// Epilogue 1 (bf16 h): h = relu(BN(l2norm(h + b2_1)))
// ---------------------------------------------------------------------------
__global__ __launch_bounds__(256) void epilogue1_bf16(
    ushort_t* __restrict__ h, const float* __restrict__ bias,
    const float* __restrict__ gamma, const float* __restrict__ beta,
    const float* __restrict__ mean, const float* __restrict__ var, int n)
{
    const int w = (blockIdx.x * 256 + threadIdx.x) >> 6;
    const int lane = threadIdx.x & 63;
    if (w >= n) return;
    ushort_t* row = h + (size_t)w * DH_;
    const int c = lane << 2;

    const uint2 u = *(const uint2*)(row + c);
    const float4 bb = *(const float4*)(bias + c);
    float v0 = bf2f((ushort_t)u.x)         + bb.x;
    float v1 = bf2f((ushort_t)(u.x >> 16)) + bb.y;
    float v2 = bf2f((ushort_t)u.y)         + bb.z;
    float v3 = bf2f((ushort_t)(u.y >> 16)) + bb.w;

    float ss = v0 * v0 + v1 * v1 + v2 * v2 + v3 * v3;
    #pragma unroll
    for (int o = 32; o > 0; o >>= 1) ss += __shfl_xor(ss, o);
    const float inv = 1.0f / fmaxf(sqrtf(ss), 1e-12f);

    const float4 g  = *(const float4*)(gamma + c);
    const float4 be = *(const float4*)(beta + c);
    const float4 mn = *(const float4*)(mean + c);
    const float4 vr = *(const float4*)(var + c);

    v0 = fmaxf(g.x * (v0 * inv - mn.x) * rsqrtf(vr.x + 1e-5f) + be.x, 0.f);
    v1 = fmaxf(g.y * (v1 * inv - mn.y) * rsqrtf(vr.y + 1e-5f) + be.y, 0.f);
    v2 = fmaxf(g.z * (v2 * inv - mn.z) * rsqrtf(vr.z + 1e-5f) + be.z, 0.f);
    v3 = fmaxf(g.w * (v3 * inv - mn.w) * rsqrtf(vr.w + 1e-5f) + be.w, 0.f);

    uint2 o;
    o.x = (uint_t)f2bf(v0) | ((uint_t)f2bf(v1) << 16);
    o.y = (uint_t)f2bf(v2) | ((uint_t)f2bf(v3) << 16);
    *(uint2*)(row + c) = o;
}

// ---------------------------------------------------------------------------
// Epilogue 2 (f32 out): out = l2norm(out + b2_2)
// ---------------------------------------------------------------------------
__global__ __launch_bounds__(256) void epilogue2_kernel(
    float* __restrict__ out, const float* __restrict__ bias, int n)
{
    const int w = (blockIdx.x * 256 + threadIdx.x) >> 6;
    const int lane = threadIdx.x & 63;
    if (w >= n) return;
    float* row = out + (size_t)w * DOUT_;
    const int c = lane << 1;

    float2 v = *(float2*)(row + c);
    const float2 bb = *(const float2*)(bias + c);
    v.x += bb.x; v.y += bb.y;

    float ss = v.x * v.x + v.y * v.y;
    #pragma unroll
    for (int o = 32; o > 0; o >>= 1) ss += __shfl_xor(ss, o);
    const float inv = 1.0f / fmaxf(sqrtf(ss), 1e-12f);

    v.x *= inv; v.y *= inv;
    *(float2*)(row + c) = v;
}

// ---------------------------------------------------------------------------
extern "C" void kernel_launch(void* const* d_in, const int* in_sizes, int n_in,
                              void* d_out, int out_size, void* d_ws, size_t ws_size,
                              hipStream_t stream)
{
    const float* x     = (const float*)d_in[0];
    const int*   src1  = (const int*)d_in[1];
    const int*   dst1  = (const int*)d_in[2];
    const int*   src2  = (const int*)d_in[3];
    const int*   dst2  = (const int*)d_in[4];
    const float* W1_1  = (const float*)d_in[7];
    const float* W2_1  = (const float*)d_in[8];
    const float* b2_1  = (const float*)d_in[9];
    const float* gamma1= (const float*)d_in[10];
    const float* beta1 = (const float*)d_in[11];
    const float* mean1 = (const float*)d_in[12];
    const float* var1  = (const float*)d_in[13];
    const float* W1_2  = (const float*)d_in[14];
    const float* W2_2  = (const float*)d_in[15];
    const float* b2_2  = (const float*)d_in[16];
    float* out = (float*)d_out;

    const int E1 = in_sizes[1];
    const int E2 = in_sizes[3];
    const int n1 = N1C;
    const int n2 = N2C;

    // Workspace layout (byte offsets), NO aliasing — ws_size ~1.024 GB
    // (fill dispatch WRITE_SIZE=1e6 KB in round-3 profile). Total ~225 MB.
    char* wsb = (char*)d_ws;
    ushort_t* xb    = (ushort_t*)(wsb + 0);            // 128,000,000
    ushort_t* h     = (ushort_t*)(wsb + 128000000);    //  51,200,000
    ushort_t* agg1  = (ushort_t*)(wsb + 179200000);    //  25,600,000
    ushort_t* agg2  = (ushort_t*)(wsb + 204800000);    //  10,240,000
    int*      esrc1 = (int*)(wsb + 215040000);         //   6,400,000
    int*      esrc2 = (int*)(wsb + 221440000);         //   1,280,000
    int*      cnt1  = (int*)(wsb + 222720000);         //     409,600 (25*4096*4)
    int*      cnt2  = (int*)(wsb + 223129600);         //      81,920 (5*4096*4)
    int*      off1  = (int*)(wsb + 223211520);         //     409,600
    int*      off2  = (int*)(wsb + 223621120);         //      81,920
    int*      pos1  = (int*)(wsb + 223703040);         //     409,600
    int*      pos2  = (int*)(wsb + 224112640);         //      81,920
    int*      bsum1 = (int*)(wsb + 224194560);         //         128
    int*      bsum2 = (int*)(wsb + 224194688);         //         128
    int*      boff1 = (int*)(wsb + 224194816);         //         128
    int*      boff2 = (int*)(wsb + 224194944);         //         128
    ushort_t* wb    = (ushort_t*)(wsb + 224195072);    //     262,144
    ushort_t* w11b = wb;
    ushort_t* w21b = wb + 32768;
    ushort_t* w12b = wb + 65536;
    ushort_t* w22b = wb + 98304;

    // --- conversions ---
    {
        const long long n8 = (long long)500000 * DIN_ / 8;
        convert_x_kernel<<<(int)((n8 + 255) / 256), 256, 0, stream>>>(x, xb, n8);
    }
    convert_weights_kernel<<<64, 256, 0, stream>>>(W1_1, W2_1, W1_2, W2_2, wb);

    // --- CSR build for BOTH graphs (parallel 3-phase scan) ---
    hipMemsetAsync(cnt1, 0, 491520, stream);  // cnt1 + cnt2 (contiguous, padded)
    {
        const int tE = E1 + E2;
        hist_both_kernel<<<(tE + 255) / 256, 256, 0, stream>>>(dst1, E1, dst2, E2, cnt1, cnt2);
        scan_partial_kernel<<<NB1 + NB2, 256, 0, stream>>>(cnt1, bsum1, cnt2, bsum2);
        scan_bsums_kernel<<<1, 128, 0, stream>>>(bsum1, boff1, bsum2, boff2);
        scan_final_kernel<<<NB1 + NB2, 256, 0, stream>>>(cnt1, boff1, off1, pos1,
                                                         cnt2, boff2, off2, pos2);
        scatter_both_kernel<<<(tE + 255) / 256, 256, 0, stream>>>(
            src1, dst1, E1, src2, dst2, E2, pos1, esrc1, pos2, esrc2);
    }

    // --- Layer 1 ---
    gather_mean_128_bf16<<<(n1 + 3) / 4, 256, 0, stream>>>(xb, off1, esrc1, agg1, n1);
    {
        dim3 grid((n1 + 127) / 128, DH_ / 128);
        gemm_dual_mfma<true><<<grid, 256, 0, stream>>>(xb, w11b, agg1, w21b, h, n1, DH_, DIN_);
    }
    epilogue1_bf16<<<(n1 + 3) / 4, 256, 0, stream>>>(h, b2_1, gamma1, beta1, mean1, var1, n1);

    // --- Layer 2 ---
    gather_mean_256_bf16<<<(n2 + 3) / 4, 256, 0, stream>>>(h, off2, esrc2, agg2, n2);
    {
        dim3 grid((n2 + 127) / 128, DOUT_ / 128);
        gemm_dual_mfma<false><<<grid, 256, 0, stream>>>(h, w12b, agg2, w22b, out, n2, DOUT_, DH_);
    }
    epilogue2_kernel<<<(n2 + 3) / 4, 256, 0, stream>>>(out, b2_2, n2);
}